// Round 8
// baseline (54.956 us; speedup 1.0000x reference)
//
#include <hip/hip_runtime.h>

// LIF membrane update, two-dispatch split-K (partials -> finalize):
//   v_new[b,n] = ALPHA*v[b,n] + sum_i x[b,i,n]*w[i,n] - V_TH*z[b,n]
//   z_new[b,n] = (v_new[b,n] - V_TH > 0) ? 1 : 0
// Shapes: x (128,1024,512) f32, w (1024,512) f32, v,z (128,512) f32.
//
// Ladder so far: R0 49.2 (frag, 1w/1x) | R2 48.8 (contig, 1w/2x, 2-disp)
// | R4 54.2 (frag, 8w/CU) | R5 61 (atomics) | R6 50.0 (contig, 1w/1x,
// 1-disp). Reading: graph dispatches are ~free; w-load amortization is
// the live lever (w = L2-resident but costs VMEM issue + L2 request BW).
//
// R7: FOUR batches per block -> 1 w-load per 4 x-loads (1.25 VMEM
// instr/x vs R2's 1.5). Block 256 thr: g=t&63 (contig 1KB wave segments),
// c=t>>6 (4-way i-split, 32 i/thread). Grid = 32 bquads x 2 slabs x 8
// igroups = 512 blocks (2/CU, 8 waves/CU; fills saturate HBM at ~3 w/CU).
// x nt-loads (stream-once); w regular (L2-resident). Finalize kernel sums
// 8 igroup partials in fixed order (deterministic) + LIF update.

typedef float f32x4 __attribute__((ext_vector_type(4)));

constexpr int B    = 128;
constexpr int N_IN = 1024;
constexpr int NN   = 512;
constexpr int NN4  = NN / 4;     // 128 f4 columns
constexpr int IG   = 8;          // igroups (split-K factor)
constexpr int IPG  = N_IN / IG;  // 128 i per group
constexpr int IPT  = IPG / 4;    // 32 i per thread
constexpr float ALPHA = 1.0f - 0.05f / 10.0f;  // 0.995
constexpr float V_TH  = 2.0f;

__global__ __launch_bounds__(256) void lif_partial(
    const f32x4* __restrict__ x4,
    const f32x4* __restrict__ w4,
    f32x4* __restrict__ part)   // [IG][B][2 slabs][64]
{
    const int t    = threadIdx.x;
    const int g    = t & 63;            // f4 column within slab
    const int c    = t >> 6;            // i-subchunk 0..3
    const int sub  = blockIdx.x & 15;   // 2 slabs x 8 igroups
    const int bq   = blockIdx.x >> 4;   // batch quad 0..31
    const int slab = sub & 1;
    const int ig   = sub >> 1;

    const int b0  = bq * 4;
    const int col = slab * 64 + g;      // f4 column 0..127
    const int i0  = ig * IPG + c * IPT;

    const size_t bstride = (size_t)N_IN * NN4;
    const f32x4* __restrict__ xp0 = x4 + (size_t)b0 * bstride + (size_t)i0 * NN4 + col;
    const f32x4* __restrict__ xp1 = xp0 + bstride;
    const f32x4* __restrict__ xp2 = xp1 + bstride;
    const f32x4* __restrict__ xp3 = xp2 + bstride;
    const f32x4* __restrict__ wp  = w4 + (size_t)i0 * NN4 + col;

    f32x4 a0 = {0.f, 0.f, 0.f, 0.f};
    f32x4 a1 = {0.f, 0.f, 0.f, 0.f};
    f32x4 a2 = {0.f, 0.f, 0.f, 0.f};
    f32x4 a3 = {0.f, 0.f, 0.f, 0.f};
    #pragma unroll 4
    for (int ii = 0; ii < IPT; ++ii) {
        const size_t off = (size_t)ii * NN4;
        f32x4 wv  = wp[off];                               // L2-hit, 1 per 4 x
        f32x4 xv0 = __builtin_nontemporal_load(&xp0[off]); // HBM stream
        f32x4 xv1 = __builtin_nontemporal_load(&xp1[off]);
        f32x4 xv2 = __builtin_nontemporal_load(&xp2[off]);
        f32x4 xv3 = __builtin_nontemporal_load(&xp3[off]);
        a0 += xv0 * wv;
        a1 += xv1 * wv;
        a2 += xv2 * wv;
        a3 += xv3 * wv;
    }

    __shared__ f32x4 red[4][256];
    red[0][t] = a0; red[1][t] = a1; red[2][t] = a2; red[3][t] = a3;
    __syncthreads();
    if (t < 128) {
        #pragma unroll
        for (int k = 0; k < 4; ++k) red[k][t] += red[k][t + 128];
    }
    __syncthreads();
    if (t < 64) {
        #pragma unroll
        for (int k = 0; k < 4; ++k) {
            f32x4 s = red[k][t] + red[k][t + 64];
            part[(((size_t)ig * B + b0 + k) * 2 + slab) * 64 + t] = s;
        }
    }
}

__global__ __launch_bounds__(256) void lif_finalize(
    const f32x4* __restrict__ part,  // [IG][B][2][64] == [IG][B][NN4]
    const f32x4* __restrict__ v4,
    const f32x4* __restrict__ z4,
    f32x4* __restrict__ vout4,
    f32x4* __restrict__ zout4)
{
    const int idx = blockIdx.x * 256 + threadIdx.x;   // over B*NN4 = 16384
    if (idx >= B * NN4) return;
    f32x4 s = part[idx];
    #pragma unroll
    for (int igr = 1; igr < IG; ++igr)                // fixed order: deterministic
        s += part[(size_t)igr * B * NN4 + idx];
    f32x4 vv = v4[idx];
    f32x4 zz = z4[idx];
    f32x4 vn = ALPHA * vv + s - V_TH * zz;
    vout4[idx] = vn;
    f32x4 zn;
    zn.x = (vn.x - V_TH > 0.f) ? 1.f : 0.f;
    zn.y = (vn.y - V_TH > 0.f) ? 1.f : 0.f;
    zn.z = (vn.z - V_TH > 0.f) ? 1.f : 0.f;
    zn.w = (vn.w - V_TH > 0.f) ? 1.f : 0.f;
    zout4[idx] = zn;
}

extern "C" void kernel_launch(void* const* d_in, const int* in_sizes, int n_in,
                              void* d_out, int out_size, void* d_ws, size_t ws_size,
                              hipStream_t stream) {
    const f32x4* x = (const f32x4*)d_in[0];
    const f32x4* w = (const f32x4*)d_in[1];
    const f32x4* v = (const f32x4*)d_in[2];
    const f32x4* z = (const f32x4*)d_in[3];
    f32x4* vout = (f32x4*)d_out;                 // v_new: B*NN floats
    f32x4* zout = vout + (size_t)B * NN4;        // z_new follows flat
    f32x4* part = (f32x4*)d_ws;                  // IG*B*NN4 f4 = 2 MB

    lif_partial<<<dim3(32 * 16), dim3(256), 0, stream>>>(x, w, part);
    lif_finalize<<<dim3((B * NN4 + 255) / 256), dim3(256), 0, stream>>>(
        part, v, z, vout, zout);
}

// Round 9
// 51.470 us; speedup vs baseline: 1.0677x; 1.0677x over previous
//
#include <hip/hip_runtime.h>

// LIF membrane update, two-dispatch split-K (partials -> finalize):
//   v_new[b,n] = ALPHA*v[b,n] + sum_i x[b,i,n]*w[i,n] - V_TH*z[b,n]
//   z_new[b,n] = (v_new[b,n] - V_TH > 0) ? 1 : 0
// Shapes: x (128,1024,512) f32, w (1024,512) f32, v,z (128,512) f32.
//
// Ladder: 16 waves/CU family ~49us (R0/R2/R6); 8 waves/CU family ~54.5
// (R4/R7); atomics 61 (R5); fence 683 (R3). Occupancy >=16 waves/CU is
// necessary for the read stream; w-amort and segment contiguity were <1.2us.
//
// R8 hypothesis: half-row slab split costs DRAM page efficiency (two
// different blocks/XCDs each read 1KB halves of the same 2KB x-row).
// This kernel = R2 exactly (1024 blk x 256 thr, 16 waves/CU, 2 batches/blk,
// nt x-loads, 2-dispatch) EXCEPT each block reads FULL 2KB rows:
//   g = t&127 -> two consecutive waves cover one contiguous 2KB row
//   c = t>>7  -> 2-way i-split within the block (32 i/thread)
//   IG = 16 igroups of 64 i across blocks.
// Finalize sums 16 partials in fixed order (deterministic) + LIF update.

typedef float f32x4 __attribute__((ext_vector_type(4)));

constexpr int B    = 128;
constexpr int N_IN = 1024;
constexpr int NN   = 512;
constexpr int NN4  = NN / 4;     // 128 f4 columns
constexpr int IG   = 16;         // igroups (split-K factor)
constexpr int IPG  = N_IN / IG;  // 64 i per group
constexpr int IPT  = IPG / 2;    // 32 i per thread
constexpr float ALPHA = 1.0f - 0.05f / 10.0f;  // 0.995
constexpr float V_TH  = 2.0f;

__global__ __launch_bounds__(256) void lif_partial(
    const f32x4* __restrict__ x4,
    const f32x4* __restrict__ w4,
    f32x4* __restrict__ part)   // [IG][B][NN4]
{
    const int t  = threadIdx.x;
    const int g  = t & 127;          // f4 column 0..127 (full row)
    const int c  = t >> 7;           // i-subchunk 0..1
    const int ig = blockIdx.x & 15;  // igroup 0..15
    const int bp = blockIdx.x >> 4;  // batch pair 0..63

    const int b0 = bp * 2;
    const int i0 = ig * IPG + c * IPT;

    const size_t bstride = (size_t)N_IN * NN4;
    const f32x4* __restrict__ xp0 = x4 + (size_t)b0 * bstride + (size_t)i0 * NN4 + g;
    const f32x4* __restrict__ xp1 = xp0 + bstride;
    const f32x4* __restrict__ wp  = w4 + (size_t)i0 * NN4 + g;

    f32x4 a0 = {0.f, 0.f, 0.f, 0.f};
    f32x4 a1 = {0.f, 0.f, 0.f, 0.f};
    #pragma unroll 4
    for (int ii = 0; ii < IPT; ++ii) {
        const size_t off = (size_t)ii * NN4;
        f32x4 wv  = wp[off];                               // L2-hit
        f32x4 xv0 = __builtin_nontemporal_load(&xp0[off]); // HBM stream, full rows
        f32x4 xv1 = __builtin_nontemporal_load(&xp1[off]);
        a0 += xv0 * wv;
        a1 += xv1 * wv;
    }

    __shared__ f32x4 red0[256];
    __shared__ f32x4 red1[256];
    red0[t] = a0;
    red1[t] = a1;
    __syncthreads();

    if (t < 128) {
        f32x4 s0 = red0[t] + red0[t + 128];
        f32x4 s1 = red1[t] + red1[t + 128];
        part[((size_t)ig * B + b0)     * NN4 + t] = s0;
        part[((size_t)ig * B + b0 + 1) * NN4 + t] = s1;
    }
}

__global__ __launch_bounds__(256) void lif_finalize(
    const f32x4* __restrict__ part,  // [IG][B][NN4]
    const f32x4* __restrict__ v4,
    const f32x4* __restrict__ z4,
    f32x4* __restrict__ vout4,
    f32x4* __restrict__ zout4)
{
    const int idx = blockIdx.x * 256 + threadIdx.x;   // over B*NN4 = 16384
    if (idx >= B * NN4) return;
    f32x4 s = part[idx];
    #pragma unroll
    for (int igr = 1; igr < IG; ++igr)                // fixed order: deterministic
        s += part[(size_t)igr * B * NN4 + idx];
    f32x4 vv = v4[idx];
    f32x4 zz = z4[idx];
    f32x4 vn = ALPHA * vv + s - V_TH * zz;
    vout4[idx] = vn;
    f32x4 zn;
    zn.x = (vn.x - V_TH > 0.f) ? 1.f : 0.f;
    zn.y = (vn.y - V_TH > 0.f) ? 1.f : 0.f;
    zn.z = (vn.z - V_TH > 0.f) ? 1.f : 0.f;
    zn.w = (vn.w - V_TH > 0.f) ? 1.f : 0.f;
    zout4[idx] = zn;
}

extern "C" void kernel_launch(void* const* d_in, const int* in_sizes, int n_in,
                              void* d_out, int out_size, void* d_ws, size_t ws_size,
                              hipStream_t stream) {
    const f32x4* x = (const f32x4*)d_in[0];
    const f32x4* w = (const f32x4*)d_in[1];
    const f32x4* v = (const f32x4*)d_in[2];
    const f32x4* z = (const f32x4*)d_in[3];
    f32x4* vout = (f32x4*)d_out;                 // v_new: B*NN floats
    f32x4* zout = vout + (size_t)B * NN4;        // z_new follows flat
    f32x4* part = (f32x4*)d_ws;                  // IG*B*NN4 f4 = 4 MB

    lif_partial<<<dim3(64 * IG), dim3(256), 0, stream>>>(x, w, part);
    lif_finalize<<<dim3((B * NN4 + 255) / 256), dim3(256), 0, stream>>>(
        part, v, z, vout, zout);
}

// Round 10
// 46.676 us; speedup vs baseline: 1.1774x; 1.1027x over previous
//
#include <hip/hip_runtime.h>

// LIF membrane update, two-dispatch split-K (partials -> finalize):
//   v_new[b,n] = ALPHA*v[b,n] + sum_i x[b,i,n]*w[i,n] - V_TH*z[b,n]
//   z_new[b,n] = (v_new[b,n] - V_TH > 0) ? 1 : 0
// Shapes: x (128,1024,512) f32, w (1024,512) f32, v,z (128,512) f32.
//
// R9 = R2 EXACTLY minus the nontemporal hint on x loads (single-variable
// A/B; nt was adopted on theory in R2 and never isolated).
// Ladder: R2 48.8 best | R0 49.2 | R6 50.0 | R8 51.5 | R4 54.2 | R7 55.0
// | R5 61 | R3 683. Core stream in R2 ~= 5.8 TB/s; floor 42.6 us.
// Structure: 1024 blocks x 256 thr (16 waves/CU), 2 batches/block (w-load
// amortized 1w/2x), g=t&63 -> contiguous 1KB wave segments, c=t>>6 4-way
// i-split (32 i/thread), IG=8 igroups. Finalize sums 8 partials in fixed
// order (deterministic) + LIF update + threshold.

typedef float f32x4 __attribute__((ext_vector_type(4)));

constexpr int B    = 128;
constexpr int N_IN = 1024;
constexpr int NN   = 512;
constexpr int NN4  = NN / 4;     // 128 f4 columns
constexpr int IG   = 8;          // igroups (split-K factor)
constexpr int IPG  = N_IN / IG;  // 128 i per group
constexpr int IPT  = IPG / 4;    // 32 i per thread
constexpr float ALPHA = 1.0f - 0.05f / 10.0f;  // 0.995
constexpr float V_TH  = 2.0f;

__global__ __launch_bounds__(256) void lif_partial(
    const f32x4* __restrict__ x4,
    const f32x4* __restrict__ w4,
    f32x4* __restrict__ part)   // [IG][B][2 slabs][64]
{
    const int t    = threadIdx.x;
    const int g    = t & 63;            // f4 column within slab (64 wide)
    const int c    = t >> 6;            // i-subchunk 0..3
    const int sub  = blockIdx.x & 15;   // 2 slabs x 8 igroups
    const int bp   = blockIdx.x >> 4;   // batch pair 0..63
    const int slab = sub & 1;
    const int ig   = sub >> 1;

    const int b0  = bp * 2;
    const int col = slab * 64 + g;      // f4 column 0..127
    const int i0  = ig * IPG + c * IPT;

    const f32x4* __restrict__ xp0 =
        x4 + ((size_t)b0 * N_IN + i0) * NN4 + col;
    const f32x4* __restrict__ xp1 = xp0 + (size_t)N_IN * NN4;
    const f32x4* __restrict__ wp  = w4 + (size_t)i0 * NN4 + col;

    f32x4 a0 = {0.f, 0.f, 0.f, 0.f};
    f32x4 a1 = {0.f, 0.f, 0.f, 0.f};
    #pragma unroll 8
    for (int ii = 0; ii < IPT; ++ii) {
        f32x4 wv  = wp[(size_t)ii * NN4];   // L2-hit (2MB, reused x128)
        f32x4 xv0 = xp0[(size_t)ii * NN4];  // plain load (A/B vs R2's nt)
        f32x4 xv1 = xp1[(size_t)ii * NN4];
        a0 += xv0 * wv;
        a1 += xv1 * wv;
    }

    __shared__ f32x4 red0[256];
    __shared__ f32x4 red1[256];
    red0[t] = a0;
    red1[t] = a1;
    __syncthreads();

    // Tree reduce over c (4 partials per column, partner stride 64 in t)
    if (t < 128) {
        red0[t] += red0[t + 128];
        red1[t] += red1[t + 128];
    }
    __syncthreads();
    if (t < 64) {
        f32x4 s0 = red0[t] + red0[t + 64];
        f32x4 s1 = red1[t] + red1[t + 64];
        const int cidx = slab * 64 + t;
        part[((size_t)ig * B + b0)     * NN4 + cidx] = s0;
        part[((size_t)ig * B + b0 + 1) * NN4 + cidx] = s1;
    }
}

__global__ __launch_bounds__(256) void lif_finalize(
    const f32x4* __restrict__ part,  // [IG][B][NN4]
    const f32x4* __restrict__ v4,
    const f32x4* __restrict__ z4,
    f32x4* __restrict__ vout4,
    f32x4* __restrict__ zout4)
{
    const int idx = blockIdx.x * 256 + threadIdx.x;   // over B*NN4 = 16384
    if (idx >= B * NN4) return;
    f32x4 s = part[idx];
    #pragma unroll
    for (int igr = 1; igr < IG; ++igr)                // fixed order: deterministic
        s += part[(size_t)igr * B * NN4 + idx];
    f32x4 vv = v4[idx];
    f32x4 zz = z4[idx];
    f32x4 vn = ALPHA * vv + s - V_TH * zz;
    vout4[idx] = vn;
    f32x4 zn;
    zn.x = (vn.x - V_TH > 0.f) ? 1.f : 0.f;
    zn.y = (vn.y - V_TH > 0.f) ? 1.f : 0.f;
    zn.z = (vn.z - V_TH > 0.f) ? 1.f : 0.f;
    zn.w = (vn.w - V_TH > 0.f) ? 1.f : 0.f;
    zout4[idx] = zn;
}

extern "C" void kernel_launch(void* const* d_in, const int* in_sizes, int n_in,
                              void* d_out, int out_size, void* d_ws, size_t ws_size,
                              hipStream_t stream) {
    const f32x4* x = (const f32x4*)d_in[0];
    const f32x4* w = (const f32x4*)d_in[1];
    const f32x4* v = (const f32x4*)d_in[2];
    const f32x4* z = (const f32x4*)d_in[3];
    f32x4* vout = (f32x4*)d_out;                 // v_new: B*NN floats
    f32x4* zout = vout + (size_t)B * NN4;        // z_new follows flat
    f32x4* part = (f32x4*)d_ws;                  // IG*B*NN4 f4 = 2 MB

    lif_partial<<<dim3(64 * 16), dim3(256), 0, stream>>>(x, w, part);
    lif_finalize<<<dim3((B * NN4 + 255) / 256), dim3(256), 0, stream>>>(
        part, v, z, vout, zout);
}